// Round 14
// baseline (4294.210 us; speedup 1.0000x reference)
//
#include <hip/hip_runtime.h>

__device__ __forceinline__ float sigm(float x) { return 1.f / (1.f + expf(-x)); }

union fu32 { float f; unsigned u; };
__device__ __forceinline__ unsigned long long packh(float h, unsigned tag) {
  fu32 c; c.f = h; return ((unsigned long long)tag << 32) | (unsigned long long)c.u;
}
// sc0 load: bypass L1, hit the XCD L2 (the fast same-XCD visibility point).
__device__ __forceinline__ unsigned long long l2_load(const unsigned long long* p) {
  unsigned long long v;
  asm volatile("global_load_dwordx2 %0, %1, off sc0\n\t"
               "s_waitcnt vmcnt(0)"
               : "=v"(v) : "v"(p) : "memory");
  return v;
}

// H=256 E=512 B=32 Tt=512 Tm=1000 MEL=80 VOCAB=256; ws f32, out FLOAT32.
constexpr size_t O_ENC  = 0;                          // [32][512][512]
constexpr size_t O_DECH = O_ENC  + 8388608;           // [32][1000][256]
constexpr size_t O_EWPK = O_DECH + 8192000;           // [8][1024][64]  (dir*4+s, tid, i)
constexpr size_t O_DWPK = O_EWPK + 524288;            // [4][1024][64]  (s, tid, i)
constexpr size_t O_EGT  = O_DWPK + 262144;            // [2][256][1024] raw gate G
constexpr size_t O_SC   = O_EGT  + 524288;            // [32][4][512]
constexpr size_t O_EBAR = O_SC   + 65536;             // [32][4][512]
constexpr size_t O_XGD  = O_EBAR + 65536;             // [32][1024] raw gate G
constexpr size_t O_U    = O_XGD  + 32768;             // [4][512]
constexpr size_t O_SB   = O_U    + 2048;              // [4] pad 16
constexpr size_t O_HGE  = O_SB   + 16;                // slow ull [64][2][256]
constexpr size_t O_HGD  = O_HGE  + 65536;             // slow ull [32][2][256]
constexpr size_t O_HGFE = O_HGD  + 32768;             // fast ull [64][2][256]
constexpr size_t O_HGFD = O_HGFE + 65536;             // fast ull [32][2][256]
constexpr size_t O_END  = O_HGFD + 32768;

// ---- prep A: weight packs (per-thread contiguous, 64/thread both scans) ----
// (hg buffers need no init: readers poll for exact tag, poison can't match)
__global__ void k_prepA(const float* __restrict__ ef_whh, const float* __restrict__ eb_whh,
                        const float* __restrict__ d_whh,
                        float* __restrict__ ewpk, float* __restrict__ dwpk) {
  int gid = blockIdx.x * 256 + threadIdx.x;
  if (gid < 524288) {              // ewpk[((dir*4+s)*1024 + tid)*64 + i] = whh[G][c]
    int i = gid & 63; int u = gid >> 6; int tid = u & 1023; int du = u >> 10;
    int dir = du >> 2, s = du & 3;
    int q = tid >> 8, r = tid & 255, tg = r >> 6, j = r & 63;
    int G = tg * 256 + s * 64 + j, c = q * 64 + i;
    ewpk[gid] = (dir ? eb_whh : ef_whh)[(size_t)G * 256 + c];
  } else if (gid < 786432) {       // dwpk[(s*1024 + tid)*64 + i] = dwhh[G][c]
    int e = gid - 524288;
    int i = e & 63; int u = e >> 6; int tid = u & 1023; int s = u >> 10;  // s<4
    int q = tid >> 8, r = tid & 255, tg = r >> 6, j = r & 63;
    int G = tg * 256 + s * 64 + j, c = q * 64 + i;
    dwpk[e] = d_whh[(size_t)G * 256 + c];
  }
}

// ---- prep B: eg[dir][v][G] = emb[v]·wih[G] + bih[G] + bhh[G] ----
__global__ void k_prepB(const float* __restrict__ emb,
                        const float* __restrict__ fw, const float* __restrict__ fb1, const float* __restrict__ fb2,
                        const float* __restrict__ bw, const float* __restrict__ bb1, const float* __restrict__ bb2,
                        float* __restrict__ egt) {
  int gid = blockIdx.x * 256 + threadIdx.x;    // < 524288
  int G = gid & 1023; int v = (gid >> 10) & 255; int dir = gid >> 18;
  const float* w = dir ? bw : fw;
  float acc = dir ? (bb1[G] + bb2[G]) : (fb1[G] + fb2[G]);
  const float4* a4 = (const float4*)(emb + (size_t)v * 256);
  const float4* w4 = (const float4*)(w + (size_t)G * 256);
  #pragma unroll 8
  for (int d = 0; d < 64; ++d) {
    float4 a = a4[d], b = w4[d];
    acc = fmaf(a.x, b.x, acc); acc = fmaf(a.y, b.y, acc);
    acc = fmaf(a.z, b.z, acc); acc = fmaf(a.w, b.w, acc);
  }
  egt[gid] = acc;
}

#define DOT64(HPTR)                                                                   \
  {                                                                                   \
    const float* hc = (HPTR) + q * 64;                                                \
    float a0 = 0.f, a1 = 0.f, a2 = 0.f, a3 = 0.f;                                     \
    _Pragma("unroll")                                                                 \
    for (int i0 = 0; i0 < 64; i0 += 16) {                                             \
      float4 h0 = *(const float4*)(hc + i0);                                          \
      float4 h1 = *(const float4*)(hc + i0 + 4);                                      \
      float4 h2 = *(const float4*)(hc + i0 + 8);                                      \
      float4 h3 = *(const float4*)(hc + i0 + 12);                                     \
      a0 = fmaf(w[i0+0], h0.x, a0); a0 = fmaf(w[i0+1], h0.y, a0);                     \
      a0 = fmaf(w[i0+2], h0.z, a0); a0 = fmaf(w[i0+3], h0.w, a0);                     \
      a1 = fmaf(w[i0+4], h1.x, a1); a1 = fmaf(w[i0+5], h1.y, a1);                     \
      a1 = fmaf(w[i0+6], h1.z, a1); a1 = fmaf(w[i0+7], h1.w, a1);                     \
      a2 = fmaf(w[i0+8], h2.x, a2); a2 = fmaf(w[i0+9], h2.y, a2);                     \
      a2 = fmaf(w[i0+10], h2.z, a2); a2 = fmaf(w[i0+11], h2.w, a2);                   \
      a3 = fmaf(w[i0+12], h3.x, a3); a3 = fmaf(w[i0+13], h3.y, a3);                   \
      a3 = fmaf(w[i0+14], h3.z, a3); a3 = fmaf(w[i0+15], h3.w, a3);                   \
    }                                                                                 \
    sh_p[tid] = (a0 + a1) + (a2 + a3);                                                \
  }

// Dual-path poll: fast = sc0 L2 load (same-XCD visibility), slow = agent/LLC
// (guaranteed). Word is self-validating (tag|h) so either path suffices.
#define POLL2(FASTP, SLOWP, IDX, TAG, DST)                                            \
  {                                                                                   \
    const unsigned tgt_ = (unsigned)(TAG);                                            \
    unsigned long long v;                                                             \
    int it_ = 0;                                                                      \
    for (;;) {                                                                        \
      v = l2_load(&(FASTP)[IDX]);                                                     \
      if ((unsigned)(v >> 32) == tgt_) break;                                         \
      if ((it_ & 3) == 3) {                                                           \
        v = __hip_atomic_load(&(SLOWP)[IDX], __ATOMIC_RELAXED,                        \
                              __HIP_MEMORY_SCOPE_AGENT);                              \
        if ((unsigned)(v >> 32) == tgt_) break;                                       \
      }                                                                               \
      ++it_;                                                                          \
      if (--budget <= 0) break;                                                       \
      __builtin_amdgcn_s_sleep(1);                                                    \
    }                                                                                 \
    fu32 c_; c_.u = (unsigned)v;                                                      \
    (DST) = c_.f;                                                                     \
  }

// ---- encoder scan: 64 chains x 4 slices = 256 WGs; dual-path (tag|h) sync ----
__global__ __launch_bounds__(1024, 4) void k_enc(
    const float* __restrict__ ewpk, const float* __restrict__ egt,
    const int* __restrict__ text, float* __restrict__ enc,
    unsigned long long* __restrict__ hg, unsigned long long* __restrict__ hgf) {
  const int wg = blockIdx.x;
  const int chain = wg & 63, s = wg >> 6;      // slice-major: chain's WGs share wg%8 XCD
  const int dir = chain >> 5, b = chain & 31;
  const int tid = threadIdx.x;
  const int q = tid >> 8;
  __shared__ float sh_h[256];
  __shared__ float sh_p[1024];
  __shared__ int sh_tok[512];
  float w[64];
  {
    const float* wp = ewpk + ((size_t)((dir * 4 + s) * 1024 + tid)) * 64;
    #pragma unroll
    for (int i = 0; i < 64; ++i) w[i] = wp[i];
  }
  if (tid < 512) sh_tok[tid] = text[b * 512 + tid];
  if (tid < 256) sh_h[tid] = 0.f;
  float cst = 0.f;
  const float* egd = egt + (size_t)dir * 262144;
  unsigned long long* hgc  = hg  + (size_t)chain * 512;
  unsigned long long* hgfc = hgf + (size_t)chain * 512;
  int budget = 60000000;
  __syncthreads();
  for (int t = 0; t < 512; ++t) {
    const int tpos = dir ? (511 - t) : t;
    float e0 = 0.f, e1 = 0.f, e2 = 0.f, e3 = 0.f;
    if (tid < 64) {                 // prefetch eg for this step (hidden behind dot)
      const float* ep = egd + (size_t)sh_tok[tpos] * 1024 + s * 64 + tid;
      e0 = ep[0]; e1 = ep[256]; e2 = ep[512]; e3 = ep[768];
    }
    DOT64(sh_h);
    __syncthreads();                // bar1: partials complete
    if (tid < 64) {
      const int j = tid;
      float gi = ((sh_p[j]       + sh_p[256 + j]) + (sh_p[512 + j] + sh_p[768 + j])) + e0;
      float gf = ((sh_p[64 + j]  + sh_p[320 + j]) + (sh_p[576 + j] + sh_p[832 + j])) + e1;
      float gg = ((sh_p[128 + j] + sh_p[384 + j]) + (sh_p[640 + j] + sh_p[896 + j])) + e2;
      float go = ((sh_p[192 + j] + sh_p[448 + j]) + (sh_p[704 + j] + sh_p[960 + j])) + e3;
      float ig = sigm(gi), fg = sigm(gf), gt = tanhf(gg), og = sigm(go);
      cst = fg * cst + ig * gt;
      float hn = og * tanhf(cst);
      if (t < 511) {
        const unsigned long long pk = packh(hn, (unsigned)(t + 1));
        hgfc[(t & 1) * 256 + s * 64 + j] = pk;   // fast: plain store -> L2 (WT L1)
        __hip_atomic_store(&hgc[(t & 1) * 256 + s * 64 + j], pk,
                           __ATOMIC_RELAXED, __HIP_MEMORY_SCOPE_AGENT);  // slow: LLC
      }
      sh_h[s * 64 + j] = hn;        // local slice: no self-poll
      enc[((size_t)b * 512 + tpos) * 512 + dir * 256 + s * 64 + j] = hn;
    }
    if (t < 511) {
      if (tid < 256 && (tid >> 6) != s) {   // poll remote 192 elements
        float hv;
        POLL2(hgfc, hgc, (t & 1) * 256 + tid, t + 1, hv);
        sh_h[tid] = hv;
      }
      __syncthreads();              // bar2: sh_h complete for next step
    }
  }
}

// ---- u[h] = wk^T·bq per head; sbias[h] = bq_h·bk_h (query==bq collapse, exact) ----
__global__ void k_att1(const float* __restrict__ aiw, const float* __restrict__ aib,
                       float* __restrict__ u, float* __restrict__ sbias) {
  int h = blockIdx.x; int e = threadIdx.x;
  float acc = 0.f;
  for (int hd = 0; hd < 128; ++hd) {
    float qv = aib[h * 128 + hd];
    acc = fmaf(qv, aiw[((size_t)(512 + h * 128 + hd)) * 512 + e], acc);
  }
  u[h * 512 + e] = acc;
  if (e == 0) {
    float sb = 0.f;
    for (int hd = 0; hd < 128; ++hd)
      sb = fmaf(aib[h * 128 + hd], aib[512 + h * 128 + hd], sb);
    sbias[h] = sb;
  }
}

__global__ void k_att2(const float* __restrict__ enc, const float* __restrict__ u,
                       const float* __restrict__ sbias, float* __restrict__ sc) {
  const int b = blockIdx.x >> 7, tile = blockIdx.x & 127;
  const int wave = threadIdx.x >> 6, lane = threadIdx.x & 63;
  const int tk = tile * 4 + wave;
  const float4* erow = (const float4*)(enc + ((size_t)b * 512 + tk) * 512);
  float4 e0 = erow[lane * 2], e1 = erow[lane * 2 + 1];
  const float4* up = (const float4*)u;
  float acc[4];
  #pragma unroll
  for (int h = 0; h < 4; ++h) {
    float4 ua = up[h * 128 + lane * 2], ub = up[h * 128 + lane * 2 + 1];
    float a = 0.f;
    a = fmaf(e0.x, ua.x, a); a = fmaf(e0.y, ua.y, a); a = fmaf(e0.z, ua.z, a); a = fmaf(e0.w, ua.w, a);
    a = fmaf(e1.x, ub.x, a); a = fmaf(e1.y, ub.y, a); a = fmaf(e1.z, ub.z, a); a = fmaf(e1.w, ub.w, a);
    acc[h] = a;
  }
  #pragma unroll
  for (int h = 0; h < 4; ++h)
    for (int m = 32; m > 0; m >>= 1) acc[h] += __shfl_xor(acc[h], m);
  if (lane == 0) {
    #pragma unroll
    for (int h = 0; h < 4; ++h)
      sc[((size_t)(b * 4 + h)) * 512 + tk] = (acc[h] + sbias[h]) * 0.08838834764831845f;
  }
}

// ---- fused softmax + ebar per (b,h) ----
__global__ void k_smeb(const float* __restrict__ sc, const float* __restrict__ enc,
                       float* __restrict__ ebar) {
  const int bh = blockIdx.x, tid = threadIdx.x;
  __shared__ float red[8];
  __shared__ float st0, st1;
  __shared__ float la[512];
  float v = sc[(size_t)bh * 512 + tid];
  float m = v;
  for (int k = 32; k > 0; k >>= 1) m = fmaxf(m, __shfl_xor(m, k));
  if ((tid & 63) == 0) red[tid >> 6] = m;
  __syncthreads();
  if (tid == 0) { float mm = red[0]; for (int i = 1; i < 8; ++i) mm = fmaxf(mm, red[i]); st0 = mm; }
  __syncthreads();
  float e = expf(v - st0);
  float s = e;
  for (int k = 32; k > 0; k >>= 1) s += __shfl_xor(s, k);
  if ((tid & 63) == 0) red[tid >> 6] = s;
  __syncthreads();
  if (tid == 0) { float ss = 0.f; for (int i = 0; i < 8; ++i) ss += red[i]; st1 = 1.f / ss; }
  __syncthreads();
  la[tid] = e * st1;
  __syncthreads();
  const int b = bh >> 2;
  const float* eb = enc + (size_t)b * 512 * 512 + tid;
  float acc = 0.f;
  #pragma unroll 8
  for (int tk = 0; tk < 512; ++tk) acc = fmaf(la[tk], eb[(size_t)tk * 512], acc);
  ebar[(size_t)bh * 512 + tid] = acc;
}

// ---- fused vout+oproj+dgate: per-batch, LDS hand-off (3 GEMVs, 1 launch) ----
__global__ __launch_bounds__(1024) void k_avx(
    const float* __restrict__ aiw, const float* __restrict__ aib,
    const float* __restrict__ aow, const float* __restrict__ aob,
    const float* __restrict__ dwih, const float* __restrict__ db1,
    const float* __restrict__ db2, const float* __restrict__ ebar,
    float* __restrict__ xgd) {
  const int b = blockIdx.x, tid = threadIdx.x;
  __shared__ float leb[2048];
  __shared__ float lvo[512];
  __shared__ float lav[512];
  leb[tid] = ebar[(size_t)b * 2048 + tid];
  leb[1024 + tid] = ebar[(size_t)b * 2048 + 1024 + tid];
  __syncthreads();
  if (tid < 512) {                 // stage 1: vo[c] = wv[c]·ebar[b,c>>7] + bv[c]
    const int h = tid >> 7;
    const float4* w4 = (const float4*)(aiw + (size_t)(1024 + tid) * 512);
    const float4* e4 = (const float4*)(leb + h * 512);
    float acc = aib[1024 + tid];
    #pragma unroll 4
    for (int e = 0; e < 128; ++e) {
      float4 ww = w4[e], ee = e4[e];
      acc = fmaf(ww.x, ee.x, acc); acc = fmaf(ww.y, ee.y, acc);
      acc = fmaf(ww.z, ee.z, acc); acc = fmaf(ww.w, ee.w, acc);
    }
    lvo[tid] = acc;
  }
  __syncthreads();
  if (tid < 512) {                 // stage 2: av[e] = out_w[e]·vo + out_b[e]
    const float4* w4 = (const float4*)(aow + (size_t)tid * 512);
    const float4* v4 = (const float4*)lvo;
    float acc = aob[tid];
    #pragma unroll 4
    for (int e = 0; e < 128; ++e) {
      float4 ww = w4[e], ee = v4[e];
      acc = fmaf(ww.x, ee.x, acc); acc = fmaf(ww.y, ee.y, acc);
      acc = fmaf(ww.z, ee.z, acc); acc = fmaf(ww.w, ee.w, acc);
    }
    lav[tid] = acc;
  }
  __syncthreads();
  {                                 // stage 3: xgd[G] = dwih[G]·av + dbih[G]+dbhh[G]
    const int G = tid;
    const float4* w4 = (const float4*)(dwih + (size_t)G * 512);
    const float4* a4 = (const float4*)lav;
    float acc = db1[G] + db2[G];
    #pragma unroll 4
    for (int e = 0; e < 128; ++e) {
      float4 ww = w4[e], aa = a4[e];
      acc = fmaf(ww.x, aa.x, acc); acc = fmaf(ww.y, aa.y, acc);
      acc = fmaf(ww.z, aa.z, acc); acc = fmaf(ww.w, aa.w, acc);
    }
    xgd[(size_t)b * 1024 + G] = acc;
  }
}

// ---- decoder scan: 32 chains x 4 slices = 128 WGs; dual-path (tag|h) sync ----
__global__ __launch_bounds__(1024, 4) void k_dec(
    const float* __restrict__ dwpk, const float* __restrict__ xgd,
    float* __restrict__ dech, unsigned long long* __restrict__ hg,
    unsigned long long* __restrict__ hgf) {
  const int wg = blockIdx.x;
  const int b = wg & 31, s = wg >> 5;          // slice-major: chain's WGs share wg%8 XCD
  const int tid = threadIdx.x;
  const int q = tid >> 8;
  __shared__ float sh_h[256];
  __shared__ float sh_p[1024];
  float w[64];
  {
    const float* wp = dwpk + ((size_t)(s * 1024 + tid)) * 64;
    #pragma unroll
    for (int i = 0; i < 64; ++i) w[i] = wp[i];
  }
  float xgi = 0.f, xgf = 0.f, xgg = 0.f, xgo = 0.f;
  if (tid < 64) {                    // wave0: own element's 4 gate biases (const over t)
    const float* xp = xgd + (size_t)b * 1024 + s * 64 + tid;
    xgi = xp[0]; xgf = xp[256]; xgg = xp[512]; xgo = xp[768];
  }
  if (tid < 256) sh_h[tid] = 0.f;
  float cst = 0.f;
  unsigned long long* hgc  = hg  + (size_t)b * 512;
  unsigned long long* hgfc = hgf + (size_t)b * 512;
  int budget = 60000000;
  __syncthreads();
  for (int t = 0; t < 1000; ++t) {
    DOT64(sh_h);
    __syncthreads();                // bar1
    if (tid < 64) {
      const int j = tid;
      float gi = ((sh_p[j]       + sh_p[256 + j]) + (sh_p[512 + j] + sh_p[768 + j])) + xgi;
      float gf = ((sh_p[64 + j]  + sh_p[320 + j]) + (sh_p[576 + j] + sh_p[832 + j])) + xgf;
      float gg = ((sh_p[128 + j] + sh_p[384 + j]) + (sh_p[640 + j] + sh_p[896 + j])) + xgg;
      float go = ((sh_p[192 + j] + sh_p[448 + j]) + (sh_p[704 + j] + sh_p[960 + j])) + xgo;
      float ig = sigm(gi), fg = sigm(gf), gt = tanhf(gg), og = sigm(go);
      cst = fg * cst + ig * gt;
      float hn = og * tanhf(cst);
      if (t < 999) {
        const unsigned long long pk = packh(hn, (unsigned)(t + 1));
        hgfc[(t & 1) * 256 + s * 64 + j] = pk;   // fast: L2
        __hip_atomic_store(&hgc[(t & 1) * 256 + s * 64 + j], pk,
                           __ATOMIC_RELAXED, __HIP_MEMORY_SCOPE_AGENT);  // slow: LLC
      }
      sh_h[s * 64 + j] = hn;        // local slice
      dech[((size_t)b * 1000 + t) * 256 + s * 64 + j] = hn;
    }
    if (t < 999) {
      if (tid < 256 && (tid >> 6) != s) {
        float hv;
        POLL2(hgfc, hgc, (t & 1) * 256 + tid, t + 1, hv);
        sh_h[tid] = hv;
      }
      __syncthreads();              // bar2
    }
  }
}

// ---- projection: out = dech @ proj_w^T + proj_b, FLOAT32 out ----
__global__ __launch_bounds__(256) void k_proj(const float* __restrict__ dech,
                                              const float* __restrict__ pw,
                                              const float* __restrict__ pb,
                                              float* __restrict__ out) {
  __shared__ float lpw[80 * 260];
  __shared__ float lpb[80];
  const int tid = threadIdx.x;
  for (int i = tid; i < 20480; i += 256) lpw[(i >> 8) * 260 + (i & 255)] = pw[i];
  if (tid < 80) lpb[tid] = pb[tid];
  __syncthreads();
  const int row0 = blockIdx.x * 16;
  const int ri = tid >> 4, mi = tid & 15;
  const float4* dr = (const float4*)(dech + (size_t)(row0 + ri) * 256);
  #pragma unroll
  for (int mt = 0; mt < 5; ++mt) {
    const int m = mt * 16 + mi;
    float acc = lpb[m];
    const float4* pw4 = (const float4*)&lpw[m * 260];
    #pragma unroll 8
    for (int d4 = 0; d4 < 64; ++d4) {
      float4 w4 = pw4[d4]; float4 x4 = dr[d4];
      acc = fmaf(w4.x, x4.x, acc); acc = fmaf(w4.y, x4.y, acc);
      acc = fmaf(w4.z, x4.z, acc); acc = fmaf(w4.w, x4.w, acc);
    }
    out[(size_t)(row0 + ri) * 80 + m] = acc;
  }
}

extern "C" void kernel_launch(void* const* d_in, const int* in_sizes, int n_in,
                              void* d_out, int out_size, void* d_ws, size_t ws_size,
                              hipStream_t stream) {
  static const int SIG[21] = {16384, 2560000, 65536,
                              262144, 262144, 1024, 1024,      // enc_f
                              262144, 262144, 1024, 1024,      // enc_b
                              786432, 1536, 262144, 512,       // attn
                              524288, 262144, 1024, 1024,      // dec
                              20480, 80};                      // proj
  if (n_in != 21) return;
  for (int i = 0; i < 21; ++i) if (in_sizes[i] != SIG[i]) return;
  if (ws_size < O_END * sizeof(float)) return;
  if (out_size != 32 * 1000 * 80) return;

  const int* text = (const int*)d_in[0];
  const float* emb    = (const float*)d_in[2];
  const float* ef_wih = (const float*)d_in[3];
  const float* ef_whh = (const float*)d_in[4];
  const float* ef_bih = (const float*)d_in[5];
  const float* ef_bhh = (const float*)d_in[6];
  const float* eb_wih = (const float*)d_in[7];
  const float* eb_whh = (const float*)d_in[8];
  const float* eb_bih = (const float*)d_in[9];
  const float* eb_bhh = (const float*)d_in[10];
  const float* aiw    = (const float*)d_in[11];
  const float* aib    = (const float*)d_in[12];
  const float* aow    = (const float*)d_in[13];
  const float* aob    = (const float*)d_in[14];
  const float* dwih   = (const float*)d_in[15];
  const float* dwhh   = (const float*)d_in[16];
  const float* dbih   = (const float*)d_in[17];
  const float* dbhh   = (const float*)d_in[18];
  const float* pw     = (const float*)d_in[19];
  const float* pb     = (const float*)d_in[20];
  float* W = (float*)d_ws;
  unsigned long long* hge  = (unsigned long long*)(W + O_HGE);
  unsigned long long* hgd  = (unsigned long long*)(W + O_HGD);
  unsigned long long* hgfe = (unsigned long long*)(W + O_HGFE);
  unsigned long long* hgfd = (unsigned long long*)(W + O_HGFD);
  float* out = (float*)d_out;

  k_prepA<<<3072, 256, 0, stream>>>(ef_whh, eb_whh, dwhh, W + O_EWPK, W + O_DWPK);
  k_prepB<<<2048, 256, 0, stream>>>(emb, ef_wih, ef_bih, ef_bhh,
                                    eb_wih, eb_bih, eb_bhh, W + O_EGT);
  k_enc<<<256, 1024, 0, stream>>>(W + O_EWPK, W + O_EGT, text, W + O_ENC, hge, hgfe);
  k_att1<<<4, 512, 0, stream>>>(aiw, aib, W + O_U, W + O_SB);
  k_att2<<<4096, 256, 0, stream>>>(W + O_ENC, W + O_U, W + O_SB, W + O_SC);
  k_smeb<<<128, 512, 0, stream>>>(W + O_SC, W + O_ENC, W + O_EBAR);
  k_avx<<<32, 1024, 0, stream>>>(aiw, aib, aow, aob, dwih, dbih, dbhh,
                                 W + O_EBAR, W + O_XGD);
  k_dec<<<128, 1024, 0, stream>>>(W + O_DWPK, W + O_XGD, W + O_DECH, hgd, hgfd);
  k_proj<<<2000, 256, 0, stream>>>(W + O_DECH, pw, pb, out);
}

// Round 15
// 3518.026 us; speedup vs baseline: 1.2206x; 1.2206x over previous
//
#include <hip/hip_runtime.h>

__device__ __forceinline__ float sigm(float x) { return 1.f / (1.f + expf(-x)); }

union fu32 { float f; unsigned u; };
__device__ __forceinline__ unsigned long long packh(float h, unsigned tag) {
  fu32 c; c.f = h; return ((unsigned long long)tag << 32) | (unsigned long long)c.u;
}

// H=256 E=512 B=32 Tt=512 Tm=1000 MEL=80 VOCAB=256; ws f32, out FLOAT32.
constexpr size_t O_ENC  = 0;                          // [32][512][512]
constexpr size_t O_DECH = O_ENC  + 8388608;           // [32][1000][256]
constexpr size_t O_EWPK = O_DECH + 8192000;           // [8][1024][64]  (dir*4+s, tid, i)
constexpr size_t O_DWPK = O_EWPK + 524288;            // [4][1024][64]  (s, tid, i)
constexpr size_t O_EGT  = O_DWPK + 262144;            // [2][256][1024] raw gate G
constexpr size_t O_SC   = O_EGT  + 524288;            // [32][4][512]
constexpr size_t O_EBAR = O_SC   + 65536;             // [32][4][512]
constexpr size_t O_XGD  = O_EBAR + 65536;             // [32][1024] raw gate G
constexpr size_t O_U    = O_XGD  + 32768;             // [4][512]
constexpr size_t O_SB   = O_U    + 2048;              // [4] pad 16
constexpr size_t O_HGE  = O_SB   + 16;                // ull [64][2][256] = 65536 f
constexpr size_t O_HGD  = O_HGE  + 65536;             // ull [32][2][256] = 32768 f
constexpr size_t O_END  = O_HGD  + 32768;

// ---- prep A: weight packs (per-thread contiguous, 64/thread both scans) ----
// (hg buffers need no init: readers poll for exact tag, poison can't match)
__global__ void k_prepA(const float* __restrict__ ef_whh, const float* __restrict__ eb_whh,
                        const float* __restrict__ d_whh,
                        float* __restrict__ ewpk, float* __restrict__ dwpk) {
  int gid = blockIdx.x * 256 + threadIdx.x;
  if (gid < 524288) {              // ewpk[((dir*4+s)*1024 + tid)*64 + i] = whh[G][c]
    int i = gid & 63; int u = gid >> 6; int tid = u & 1023; int du = u >> 10;
    int dir = du >> 2, s = du & 3;
    int q = tid >> 8, r = tid & 255, tg = r >> 6, j = r & 63;
    int G = tg * 256 + s * 64 + j, c = q * 64 + i;
    ewpk[gid] = (dir ? eb_whh : ef_whh)[(size_t)G * 256 + c];
  } else if (gid < 786432) {       // dwpk[(s*1024 + tid)*64 + i] = dwhh[G][c]
    int e = gid - 524288;
    int i = e & 63; int u = e >> 6; int tid = u & 1023; int s = u >> 10;  // s<4
    int q = tid >> 8, r = tid & 255, tg = r >> 6, j = r & 63;
    int G = tg * 256 + s * 64 + j, c = q * 64 + i;
    dwpk[e] = d_whh[(size_t)G * 256 + c];
  }
}

// ---- prep B: eg[dir][v][G] = emb[v]·wih[G] + bih[G] + bhh[G] ----
__global__ void k_prepB(const float* __restrict__ emb,
                        const float* __restrict__ fw, const float* __restrict__ fb1, const float* __restrict__ fb2,
                        const float* __restrict__ bw, const float* __restrict__ bb1, const float* __restrict__ bb2,
                        float* __restrict__ egt) {
  int gid = blockIdx.x * 256 + threadIdx.x;    // < 524288
  int G = gid & 1023; int v = (gid >> 10) & 255; int dir = gid >> 18;
  const float* w = dir ? bw : fw;
  float acc = dir ? (bb1[G] + bb2[G]) : (fb1[G] + fb2[G]);
  const float4* a4 = (const float4*)(emb + (size_t)v * 256);
  const float4* w4 = (const float4*)(w + (size_t)G * 256);
  #pragma unroll 8
  for (int d = 0; d < 64; ++d) {
    float4 a = a4[d], b = w4[d];
    acc = fmaf(a.x, b.x, acc); acc = fmaf(a.y, b.y, acc);
    acc = fmaf(a.z, b.z, acc); acc = fmaf(a.w, b.w, acc);
  }
  egt[gid] = acc;
}

// ---- encoder scan: 64 chains x 4 slices = 256 WGs; packed (tag|h) sync (R10) ----
__global__ __launch_bounds__(1024, 4) void k_enc(
    const float* __restrict__ ewpk, const float* __restrict__ egt,
    const int* __restrict__ text, float* __restrict__ enc,
    unsigned long long* __restrict__ hg) {
  const int wg = blockIdx.x;
  const int chain = wg & 63, s = wg >> 6;      // slice-major: chain's WGs share wg%8 XCD
  const int dir = chain >> 5, b = chain & 31;
  const int tid = threadIdx.x;
  const int q = tid >> 8;
  __shared__ float sh_h[256];
  __shared__ float sh_p[1024];
  __shared__ float sh_a[256];
  float w[64];
  {
    const float* wp = ewpk + ((size_t)((dir * 4 + s) * 1024 + tid)) * 64;
    #pragma unroll
    for (int i = 0; i < 64; ++i) w[i] = wp[i];
  }
  if (tid < 256) sh_h[tid] = 0.f;
  float cst = 0.f;
  const float* egd = egt + (size_t)dir * 262144;
  unsigned long long* hgc = hg + (size_t)chain * 512;
  int budget = 20000000;
  __syncthreads();
  for (int t = 0; t < 512; ++t) {
    const int tpos = dir ? (511 - t) : t;
    const int tok = text[b * 512 + tpos];
    float egv = 0.f;
    if (tid < 256)
      egv = egd[(size_t)tok * 1024 + ((tid >> 6) * 256 + s * 64 + (tid & 63))];
    float a0 = 0.f, a1 = 0.f, a2 = 0.f, a3 = 0.f;
    const float* hc = sh_h + q * 64;
    #pragma unroll
    for (int i0 = 0; i0 < 64; i0 += 16) {
      float4 h0 = *(const float4*)(hc + i0);
      float4 h1 = *(const float4*)(hc + i0 + 4);
      float4 h2 = *(const float4*)(hc + i0 + 8);
      float4 h3 = *(const float4*)(hc + i0 + 12);
      a0 = fmaf(w[i0+0], h0.x, a0); a0 = fmaf(w[i0+1], h0.y, a0); a0 = fmaf(w[i0+2], h0.z, a0); a0 = fmaf(w[i0+3], h0.w, a0);
      a1 = fmaf(w[i0+4], h1.x, a1); a1 = fmaf(w[i0+5], h1.y, a1); a1 = fmaf(w[i0+6], h1.z, a1); a1 = fmaf(w[i0+7], h1.w, a1);
      a2 = fmaf(w[i0+8], h2.x, a2); a2 = fmaf(w[i0+9], h2.y, a2); a2 = fmaf(w[i0+10], h2.z, a2); a2 = fmaf(w[i0+11], h2.w, a2);
      a3 = fmaf(w[i0+12], h3.x, a3); a3 = fmaf(w[i0+13], h3.y, a3); a3 = fmaf(w[i0+14], h3.z, a3); a3 = fmaf(w[i0+15], h3.w, a3);
    }
    sh_p[tid] = (a0 + a1) + (a2 + a3);
    __syncthreads();
    if (tid < 256) {
      float g = ((sh_p[tid] + sh_p[256 + tid]) + (sh_p[512 + tid] + sh_p[768 + tid])) + egv;
      sh_a[tid] = ((tid >> 6) == 2) ? tanhf(g) : sigm(g);
    }
    __syncthreads();
    if (tid < 64) {   // wave 0: state update; publish (tag|h) — data IS the flag
      float ig = sh_a[tid], fg = sh_a[64 + tid], gg = sh_a[128 + tid], og = sh_a[192 + tid];
      cst = fg * cst + ig * gg;
      float hn = og * tanhf(cst);
      if (t < 511)
        __hip_atomic_store(&hgc[(t & 1) * 256 + s * 64 + tid], packh(hn, (unsigned)(t + 1)),
                           __ATOMIC_RELAXED, __HIP_MEMORY_SCOPE_AGENT);
      enc[((size_t)b * 512 + tpos) * 512 + dir * 256 + s * 64 + tid] = hn;  // off crit. path
    }
    if (t < 511) {
      if (tid < 256) {   // poll own element: tag match delivers h in the same word
        const unsigned tgt = (unsigned)(t + 1);
        unsigned long long v;
        for (;;) {
          v = __hip_atomic_load(&hgc[(t & 1) * 256 + tid],
                                __ATOMIC_RELAXED, __HIP_MEMORY_SCOPE_AGENT);
          if ((unsigned)(v >> 32) == tgt || --budget <= 0) break;
          __builtin_amdgcn_s_sleep(1);
        }
        fu32 c; c.u = (unsigned)v;
        sh_h[tid] = c.f;
      }
      __syncthreads();
    }
  }
}

// ---- u[h] = wk^T·bq per head; sbias[h] = bq_h·bk_h (query==bq collapse, exact) ----
__global__ void k_att1(const float* __restrict__ aiw, const float* __restrict__ aib,
                       float* __restrict__ u, float* __restrict__ sbias) {
  int h = blockIdx.x; int e = threadIdx.x;
  float acc = 0.f;
  for (int hd = 0; hd < 128; ++hd) {
    float qv = aib[h * 128 + hd];
    acc = fmaf(qv, aiw[((size_t)(512 + h * 128 + hd)) * 512 + e], acc);
  }
  u[h * 512 + e] = acc;
  if (e == 0) {
    float sb = 0.f;
    for (int hd = 0; hd < 128; ++hd)
      sb = fmaf(aib[h * 128 + hd], aib[512 + h * 128 + hd], sb);
    sbias[h] = sb;
  }
}

__global__ void k_att2(const float* __restrict__ enc, const float* __restrict__ u,
                       const float* __restrict__ sbias, float* __restrict__ sc) {
  const int b = blockIdx.x >> 7, tile = blockIdx.x & 127;
  const int wave = threadIdx.x >> 6, lane = threadIdx.x & 63;
  const int tk = tile * 4 + wave;
  const float4* erow = (const float4*)(enc + ((size_t)b * 512 + tk) * 512);
  float4 e0 = erow[lane * 2], e1 = erow[lane * 2 + 1];
  const float4* up = (const float4*)u;
  float acc[4];
  #pragma unroll
  for (int h = 0; h < 4; ++h) {
    float4 ua = up[h * 128 + lane * 2], ub = up[h * 128 + lane * 2 + 1];
    float a = 0.f;
    a = fmaf(e0.x, ua.x, a); a = fmaf(e0.y, ua.y, a); a = fmaf(e0.z, ua.z, a); a = fmaf(e0.w, ua.w, a);
    a = fmaf(e1.x, ub.x, a); a = fmaf(e1.y, ub.y, a); a = fmaf(e1.z, ub.z, a); a = fmaf(e1.w, ub.w, a);
    acc[h] = a;
  }
  #pragma unroll
  for (int h = 0; h < 4; ++h)
    for (int m = 32; m > 0; m >>= 1) acc[h] += __shfl_xor(acc[h], m);
  if (lane == 0) {
    #pragma unroll
    for (int h = 0; h < 4; ++h)
      sc[((size_t)(b * 4 + h)) * 512 + tk] = (acc[h] + sbias[h]) * 0.08838834764831845f;
  }
}

// ---- fused softmax + ebar per (b,h) (validated R12-R14, identical absmax) ----
__global__ void k_smeb(const float* __restrict__ sc, const float* __restrict__ enc,
                       float* __restrict__ ebar) {
  const int bh = blockIdx.x, tid = threadIdx.x;
  __shared__ float red[8];
  __shared__ float st0, st1;
  __shared__ float la[512];
  float v = sc[(size_t)bh * 512 + tid];
  float m = v;
  for (int k = 32; k > 0; k >>= 1) m = fmaxf(m, __shfl_xor(m, k));
  if ((tid & 63) == 0) red[tid >> 6] = m;
  __syncthreads();
  if (tid == 0) { float mm = red[0]; for (int i = 1; i < 8; ++i) mm = fmaxf(mm, red[i]); st0 = mm; }
  __syncthreads();
  float e = expf(v - st0);
  float s = e;
  for (int k = 32; k > 0; k >>= 1) s += __shfl_xor(s, k);
  if ((tid & 63) == 0) red[tid >> 6] = s;
  __syncthreads();
  if (tid == 0) { float ss = 0.f; for (int i = 0; i < 8; ++i) ss += red[i]; st1 = 1.f / ss; }
  __syncthreads();
  la[tid] = e * st1;
  __syncthreads();
  const int b = bh >> 2;
  const float* eb = enc + (size_t)b * 512 * 512 + tid;
  float acc = 0.f;
  #pragma unroll 8
  for (int tk = 0; tk < 512; ++tk) acc = fmaf(la[tk], eb[(size_t)tk * 512], acc);
  ebar[(size_t)bh * 512 + tid] = acc;
}

// ---- fused vout+oproj+dgate: per-batch, LDS hand-off (3 GEMVs, 1 launch) ----
__global__ __launch_bounds__(1024) void k_avx(
    const float* __restrict__ aiw, const float* __restrict__ aib,
    const float* __restrict__ aow, const float* __restrict__ aob,
    const float* __restrict__ dwih, const float* __restrict__ db1,
    const float* __restrict__ db2, const float* __restrict__ ebar,
    float* __restrict__ xgd) {
  const int b = blockIdx.x, tid = threadIdx.x;
  __shared__ float leb[2048];
  __shared__ float lvo[512];
  __shared__ float lav[512];
  leb[tid] = ebar[(size_t)b * 2048 + tid];
  leb[1024 + tid] = ebar[(size_t)b * 2048 + 1024 + tid];
  __syncthreads();
  if (tid < 512) {                 // stage 1: vo[c] = wv[c]·ebar[b,c>>7] + bv[c]
    const int h = tid >> 7;
    const float4* w4 = (const float4*)(aiw + (size_t)(1024 + tid) * 512);
    const float4* e4 = (const float4*)(leb + h * 512);
    float acc = aib[1024 + tid];
    #pragma unroll 4
    for (int e = 0; e < 128; ++e) {
      float4 ww = w4[e], ee = e4[e];
      acc = fmaf(ww.x, ee.x, acc); acc = fmaf(ww.y, ee.y, acc);
      acc = fmaf(ww.z, ee.z, acc); acc = fmaf(ww.w, ee.w, acc);
    }
    lvo[tid] = acc;
  }
  __syncthreads();
  if (tid < 512) {                 // stage 2: av[e] = out_w[e]·vo + out_b[e]
    const float4* w4 = (const float4*)(aow + (size_t)tid * 512);
    const float4* v4 = (const float4*)lvo;
    float acc = aob[tid];
    #pragma unroll 4
    for (int e = 0; e < 128; ++e) {
      float4 ww = w4[e], ee = v4[e];
      acc = fmaf(ww.x, ee.x, acc); acc = fmaf(ww.y, ee.y, acc);
      acc = fmaf(ww.z, ee.z, acc); acc = fmaf(ww.w, ee.w, acc);
    }
    lav[tid] = acc;
  }
  __syncthreads();
  {                                 // stage 3: xgd[G] = dwih[G]·av + dbih[G]+dbhh[G]
    const int G = tid;
    const float4* w4 = (const float4*)(dwih + (size_t)G * 512);
    const float4* a4 = (const float4*)lav;
    float acc = db1[G] + db2[G];
    #pragma unroll 4
    for (int e = 0; e < 128; ++e) {
      float4 ww = w4[e], aa = a4[e];
      acc = fmaf(ww.x, aa.x, acc); acc = fmaf(ww.y, aa.y, acc);
      acc = fmaf(ww.z, aa.z, acc); acc = fmaf(ww.w, aa.w, acc);
    }
    xgd[(size_t)b * 1024 + G] = acc;
  }
}

// ---- decoder scan: 32 chains x 4 slices = 128 WGs; packed (tag|h) sync (R10) ----
__global__ __launch_bounds__(1024, 4) void k_dec(
    const float* __restrict__ dwpk, const float* __restrict__ xgd,
    float* __restrict__ dech, unsigned long long* __restrict__ hg) {
  const int wg = blockIdx.x;
  const int b = wg & 31, s = wg >> 5;          // slice-major: chain's WGs share wg%8 XCD
  const int tid = threadIdx.x;
  const int q = tid >> 8;
  __shared__ float sh_h[256];
  __shared__ float sh_p[1024];
  __shared__ float sh_a[256];
  float w[64];
  {
    const float* wp = dwpk + ((size_t)(s * 1024 + tid)) * 64;
    #pragma unroll
    for (int i = 0; i < 64; ++i) w[i] = wp[i];
  }
  float xg = 0.f;
  if (tid < 256)
    xg = xgd[(size_t)b * 1024 + ((tid >> 6) * 256 + s * 64 + (tid & 63))];
  if (tid < 256) sh_h[tid] = 0.f;
  float cst = 0.f;
  unsigned long long* hgc = hg + (size_t)b * 512;
  int budget = 20000000;
  __syncthreads();
  for (int t = 0; t < 1000; ++t) {
    float a0 = 0.f, a1 = 0.f, a2 = 0.f, a3 = 0.f;
    const float* hc = sh_h + q * 64;
    #pragma unroll
    for (int i0 = 0; i0 < 64; i0 += 16) {
      float4 h0 = *(const float4*)(hc + i0);
      float4 h1 = *(const float4*)(hc + i0 + 4);
      float4 h2 = *(const float4*)(hc + i0 + 8);
      float4 h3 = *(const float4*)(hc + i0 + 12);
      a0 = fmaf(w[i0+0], h0.x, a0); a0 = fmaf(w[i0+1], h0.y, a0); a0 = fmaf(w[i0+2], h0.z, a0); a0 = fmaf(w[i0+3], h0.w, a0);
      a1 = fmaf(w[i0+4], h1.x, a1); a1 = fmaf(w[i0+5], h1.y, a1); a1 = fmaf(w[i0+6], h1.z, a1); a1 = fmaf(w[i0+7], h1.w, a1);
      a2 = fmaf(w[i0+8], h2.x, a2); a2 = fmaf(w[i0+9], h2.y, a2); a2 = fmaf(w[i0+10], h2.z, a2); a2 = fmaf(w[i0+11], h2.w, a2);
      a3 = fmaf(w[i0+12], h3.x, a3); a3 = fmaf(w[i0+13], h3.y, a3); a3 = fmaf(w[i0+14], h3.z, a3); a3 = fmaf(w[i0+15], h3.w, a3);
    }
    sh_p[tid] = (a0 + a1) + (a2 + a3);
    __syncthreads();
    if (tid < 256) {
      float g = ((sh_p[tid] + sh_p[256 + tid]) + (sh_p[512 + tid] + sh_p[768 + tid])) + xg;
      sh_a[tid] = ((tid >> 6) == 2) ? tanhf(g) : sigm(g);
    }
    __syncthreads();
    if (tid < 64) {
      float ig = sh_a[tid], fg = sh_a[64 + tid], gg = sh_a[128 + tid], og = sh_a[192 + tid];
      cst = fg * cst + ig * gg;
      float hn = og * tanhf(cst);
      if (t < 999)
        __hip_atomic_store(&hgc[(t & 1) * 256 + s * 64 + tid], packh(hn, (unsigned)(t + 1)),
                           __ATOMIC_RELAXED, __HIP_MEMORY_SCOPE_AGENT);
      dech[((size_t)b * 1000 + t) * 256 + s * 64 + tid] = hn;   // off crit. path
    }
    if (t < 999) {
      if (tid < 256) {
        const unsigned tgt = (unsigned)(t + 1);
        unsigned long long v;
        for (;;) {
          v = __hip_atomic_load(&hgc[(t & 1) * 256 + tid],
                                __ATOMIC_RELAXED, __HIP_MEMORY_SCOPE_AGENT);
          if ((unsigned)(v >> 32) == tgt || --budget <= 0) break;
          __builtin_amdgcn_s_sleep(1);
        }
        fu32 c; c.u = (unsigned)v;
        sh_h[tid] = c.f;
      }
      __syncthreads();
    }
  }
}

// ---- projection: out = dech @ proj_w^T + proj_b, FLOAT32 out ----
__global__ __launch_bounds__(256) void k_proj(const float* __restrict__ dech,
                                              const float* __restrict__ pw,
                                              const float* __restrict__ pb,
                                              float* __restrict__ out) {
  __shared__ float lpw[80 * 260];
  __shared__ float lpb[80];
  const int tid = threadIdx.x;
  for (int i = tid; i < 20480; i += 256) lpw[(i >> 8) * 260 + (i & 255)] = pw[i];
  if (tid < 80) lpb[tid] = pb[tid];
  __syncthreads();
  const int row0 = blockIdx.x * 16;
  const int ri = tid >> 4, mi = tid & 15;
  const float4* dr = (const float4*)(dech + (size_t)(row0 + ri) * 256);
  #pragma unroll
  for (int mt = 0; mt < 5; ++mt) {
    const int m = mt * 16 + mi;
    float acc = lpb[m];
    const float4* pw4 = (const float4*)&lpw[m * 260];
    #pragma unroll 8
    for (int d4 = 0; d4 < 64; ++d4) {
      float4 w4 = pw4[d4]; float4 x4 = dr[d4];
      acc = fmaf(w4.x, x4.x, acc); acc = fmaf(w4.y, x4.y, acc);
      acc = fmaf(w4.z, x4.z, acc); acc = fmaf(w4.w, x4.w, acc);
    }
    out[(size_t)(row0 + ri) * 80 + m] = acc;
  }
}

extern "C" void kernel_launch(void* const* d_in, const int* in_sizes, int n_in,
                              void* d_out, int out_size, void* d_ws, size_t ws_size,
                              hipStream_t stream) {
  static const int SIG[21] = {16384, 2560000, 65536,
                              262144, 262144, 1024, 1024,      // enc_f
                              262144, 262144, 1024, 1024,      // enc_b
                              786432, 1536, 262144, 512,       // attn
                              524288, 262144, 1024, 1024,      // dec
                              20480, 80};                      // proj
  if (n_in != 21) return;
  for (int i = 0; i < 21; ++i) if (in_sizes[i] != SIG[i]) return;
  if (ws_size < O_END * sizeof(float)) return;
  if (out_size != 32 * 1000 * 80) return;

  const int* text = (const int*)d_in[0];
  const float* emb    = (const float*)d_in[2];
  const float* ef_wih = (const float*)d_in[3];
  const float* ef_whh = (const float*)d_in[4];
  const float* ef_bih = (const float*)d_in[5];
  const float* ef_bhh = (const float*)d_in[6];
  const float* eb_wih = (const float*)d_in[7];
  const float* eb_whh = (const float*)d_in[8];
  const float* eb_bih = (const float*)d_in[9];
  const float* eb_bhh = (const float*)d_in[10];
  const float* aiw    = (const float*)d_in[11];
  const float* aib    = (const float*)d_in[12];
  const float* aow    = (const float*)d_in[13];
  const float* aob    = (const float*)d_in[14];
  const float* dwih   = (const float*)d_in[15];
  const float* dwhh   = (const float*)d_in[16];
  const float* dbih   = (const float*)d_in[17];
  const float* dbhh   = (const float*)d_in[18];
  const float* pw     = (const float*)d_in[19];
  const float* pb     = (const float*)d_in[20];
  float* W = (float*)d_ws;
  unsigned long long* hge = (unsigned long long*)(W + O_HGE);
  unsigned long long* hgd = (unsigned long long*)(W + O_HGD);
  float* out = (float*)d_out;

  k_prepA<<<3072, 256, 0, stream>>>(ef_whh, eb_whh, dwhh, W + O_EWPK, W + O_DWPK);
  k_prepB<<<2048, 256, 0, stream>>>(emb, ef_wih, ef_bih, ef_bhh,
                                    eb_wih, eb_bih, eb_bhh, W + O_EGT);
  k_enc<<<256, 1024, 0, stream>>>(W + O_EWPK, W + O_EGT, text, W + O_ENC, hge);
  k_att1<<<4, 512, 0, stream>>>(aiw, aib, W + O_U, W + O_SB);
  k_att2<<<4096, 256, 0, stream>>>(W + O_ENC, W + O_U, W + O_SB, W + O_SC);
  k_smeb<<<128, 512, 0, stream>>>(W + O_SC, W + O_ENC, W + O_EBAR);
  k_avx<<<32, 1024, 0, stream>>>(aiw, aib, aow, aob, dwih, dbih, dbhh,
                                 W + O_EBAR, W + O_XGD);
  k_dec<<<128, 1024, 0, stream>>>(W + O_DWPK, W + O_XGD, W + O_DECH, hgd);
  k_proj<<<2000, 256, 0, stream>>>(W + O_DECH, pw, pb, out);
}